// Round 12
// baseline (19.676 us; speedup 1.0000x reference)
//
#include <hip/hip_runtime.h>
#include <hip/hip_bf16.h>

#define NB 64
#define LQ 32
#define LD 256
#define DD 128
#define NWAY 8
#define KT 64            // doc rows per tile; 4 tiles
#define NBLOCKS (NB * NWAY)   // 512
#define LDSROW 136       // 128 + 8 bf16 pad -> 272B row stride, 16B aligned

typedef __attribute__((ext_vector_type(8))) short short8;
typedef __attribute__((ext_vector_type(4))) float f32x4;

static __device__ __forceinline__ unsigned short f2bf(float f) {
    unsigned int u = __float_as_uint(f);
    u += 0x7fffu + ((u >> 16) & 1u);   // round-to-nearest-even
    return (unsigned short)(u >> 16);
}
static __device__ __forceinline__ unsigned int pk2(float a, float b) {
    return (unsigned int)f2bf(a) | ((unsigned int)f2bf(b) << 16);
}

// One block per (b,n), 512 threads = 8 waves (wave = kq*2+qh).
// b=bid&63, n=bid>>6: the 8 blocks sharing b land on one XCD -> Q L2-hits.
// R10 pipeline + occupancy push: launch_bounds(512,6) caps VGPR at 85 ->
// 3 blocks/CU = 24 waves/CU (LDS 44.5KB x3 = 133.6KB fits). Column mask gate
// folded into rnds as a sentinel (-1 = masked) to drop cmask[4] regs.
// Doc rows unnormalized bf16; 1/||d|| post-MFMA (max commutes with positive
// scales). Masked rows never loaded.
__global__ __launch_bounds__(512, 6) void colbert_scores_kernel(
    const float* __restrict__ qreps,   // [B][LQ][DD]
    const float* __restrict__ dreps,   // [B][NWAY][LD][DD]
    const int*   __restrict__ masks,   // [B][NWAY][LD]
    float*       __restrict__ scores)  // [512]
{
    const int bid  = blockIdx.x;
    const int b    = bid & 63;
    const int n    = bid >> 6;
    const int bn   = b * NWAY + n;
    const int tid  = threadIdx.x;
    const int lane = tid & 63;
    const int w    = tid >> 6;

    __shared__ __align__(16) unsigned short qs[LQ * LDSROW];       // normalized q bf16
    __shared__ __align__(16) unsigned short dsb[2][KT * LDSROW];   // raw doc bf16, dbuf
    __shared__ float rnds[2][KT];      // 1/||d|| or -1 sentinel for masked rows
    __shared__ float qmaxs[4][LQ];

    const int row = tid >> 3;          // doc staging row (0..63)
    const int seg = tid & 7;           // 16-float segment
    const int fr  = lane & 15;
    const int fp  = lane >> 4;
    const int qh  = w & 1;
    const int kq  = w >> 1;            // 0..3

    // ---- cycle 0: row-gate masks -> registers ----
    int mymask[4];
    #pragma unroll
    for (int t = 0; t < 4; ++t)
        mymask[t] = masks[(size_t)bn * LD + t * KT + row];

    // ---- Q: 16 threads/row (8 floats each), issue loads early ----
    {
        const int qrow = tid >> 4;     // 0..31
        const int qseg = tid & 15;     // 8-float segment
        const float* qsrc = qreps + ((size_t)b * LQ + qrow) * DD + qseg * 8;
        float4 qa = reinterpret_cast<const float4*>(qsrc)[0];
        float4 qb = reinterpret_cast<const float4*>(qsrc)[1];
        float ss = qa.x*qa.x + qa.y*qa.y + qa.z*qa.z + qa.w*qa.w
                 + qb.x*qb.x + qb.y*qb.y + qb.z*qb.z + qb.w*qb.w;
        ss += __shfl_xor(ss, 1); ss += __shfl_xor(ss, 2);
        ss += __shfl_xor(ss, 4); ss += __shfl_xor(ss, 8);
        const float rn = rsqrtf(fmaxf(ss, 1e-24f));
        unsigned int qp[4] = { pk2(qa.x*rn, qa.y*rn), pk2(qa.z*rn, qa.w*rn),
                               pk2(qb.x*rn, qb.y*rn), pk2(qb.z*rn, qb.w*rn) };
        unsigned short* dst = &qs[qrow * LDSROW + qseg * 8];
        *reinterpret_cast<uint4*>(dst) = *reinterpret_cast<const uint4*>(qp);
    }

    float va[16], vb[16];

    // gated on REGISTER mask -> doc loads issue with no barrier dependency
    auto prefetch = [&](float (&v)[16], int t) {
        if (mymask[t]) {
            const float* src = dreps + ((size_t)bn * LD + t * KT + row) * DD + seg * 16;
            #pragma unroll
            for (int i = 0; i < 4; ++i) {
                float4 f = reinterpret_cast<const float4*>(src)[i];
                v[4*i] = f.x; v[4*i+1] = f.y; v[4*i+2] = f.z; v[4*i+3] = f.w;
            }
        }
    };
    // pack-only staging; rnds gets -1 sentinel for masked rows.
    // mymask uniform across the row's 8 lanes -> shfl convergent.
    auto stagewrite = [&](float (&v)[16], int t, int bf) {
        float rv = -1.0f;
        if (mymask[t]) {
            unsigned int dp[8];
            #pragma unroll
            for (int i = 0; i < 8; ++i) dp[i] = pk2(v[2*i], v[2*i+1]);
            unsigned short* dst = &dsb[bf][row * LDSROW + seg * 16];
            reinterpret_cast<uint4*>(dst)[0] = *reinterpret_cast<const uint4*>(&dp[0]);
            reinterpret_cast<uint4*>(dst)[1] = *reinterpret_cast<const uint4*>(&dp[4]);
            float ss = 0.f;
            #pragma unroll
            for (int i = 0; i < 16; ++i) ss += v[i] * v[i];
            ss += __shfl_xor(ss, 1); ss += __shfl_xor(ss, 2); ss += __shfl_xor(ss, 4);
            rv = rsqrtf(fmaxf(ss, 1e-24f));
        }
        if (seg == 0) rnds[bf][row] = rv;
    };

    float rmax[4] = {-1e30f, -1e30f, -1e30f, -1e30f};
    short8 afr[4];

    auto mfma_max = [&](int t, int bf) {
        const int drow = kq * 16 + fr;     // doc row within tile -> output column
        const unsigned short* bptr = &dsb[bf][drow * LDSROW + fp * 8];
        f32x4 acc = {0.f, 0.f, 0.f, 0.f};
        #pragma unroll
        for (int kc = 0; kc < 4; ++kc) {
            short8 bb = *reinterpret_cast<const short8*>(bptr + kc * 32);
            acc = __builtin_amdgcn_mfma_f32_16x16x32_bf16(afr[kc], bb, acc, 0, 0, 0);
        }
        const float rnd = rnds[bf][drow];
        if (rnd > 0.f) {                   // sentinel gate (=column mask)
            #pragma unroll
            for (int r = 0; r < 4; ++r) rmax[r] = fmaxf(rmax[r], acc[r] * rnd);
        }
    };

    // ---- 4-tile pipeline, 2 LDS buffers, distance-2 register prefetch ----
    prefetch(va, 0);  prefetch(vb, 1);
    stagewrite(va, 0, 0);
    __syncthreads();               // dsb[0] (t0) + qs ready

    // hoist A-fragments once (register reuse across all 4 tiles)
    {
        const unsigned short* ap = &qs[(qh * 16 + fr) * LDSROW + fp * 8];
        #pragma unroll
        for (int kc = 0; kc < 4; ++kc)
            afr[kc] = *reinterpret_cast<const short8*>(ap + kc * 32);
    }

    prefetch(va, 2);
    mfma_max(0, 0);                // read dsb[0]
    stagewrite(vb, 1, 1);          // write dsb[1]
    __syncthreads();               // dsb[1] (t1) ready, dsb[0] free
    prefetch(vb, 3);
    mfma_max(1, 1);
    stagewrite(va, 2, 0);
    __syncthreads();
    mfma_max(2, 0);
    stagewrite(vb, 3, 1);
    __syncthreads();
    mfma_max(3, 1);

    // ---- reduce max over 16 doc-columns within wave ----
    #pragma unroll
    for (int r = 0; r < 4; ++r) {
        float m = rmax[r];
        m = fmaxf(m, __shfl_xor(m, 1));
        m = fmaxf(m, __shfl_xor(m, 2));
        m = fmaxf(m, __shfl_xor(m, 4));
        m = fmaxf(m, __shfl_xor(m, 8));
        rmax[r] = m;
    }
    if (fr == 0) {
        const int qr = qh * 16 + fp * 4;
        #pragma unroll
        for (int r = 0; r < 4; ++r) qmaxs[kq][qr + r] = rmax[r];
    }
    __syncthreads();

    // ---- combine k-quarters, sum over q rows, store score ----
    if (w == 0) {
        float s = 0.f;
        if (lane < 32)
            s = fmaxf(fmaxf(qmaxs[0][lane], qmaxs[1][lane]),
                      fmaxf(qmaxs[2][lane], qmaxs[3][lane]));
        s += __shfl_xor(s, 1);  s += __shfl_xor(s, 2);  s += __shfl_xor(s, 4);
        s += __shfl_xor(s, 8);  s += __shfl_xor(s, 16); s += __shfl_xor(s, 32);
        if (lane == 0) scores[bn] = s;
    }
}

// One wave: thread b handles batch row b.
__global__ __launch_bounds__(64) void colbert_loss_kernel(
    const float* __restrict__ scores,   // [512]
    const float* __restrict__ labels,   // [B][2*NWAY]
    float*       __restrict__ out)
{
    const int b = threadIdx.x;
    float sc[NWAY];
    float m = -1e30f;
    #pragma unroll
    for (int j = 0; j < NWAY; ++j) { sc[j] = scores[b * NWAY + j]; m = fmaxf(m, sc[j]); }
    float se = 0.f;
    #pragma unroll
    for (int j = 0; j < NWAY; ++j) se += expf(sc[j] - m);
    const float lse = m + logf(se);

    float lossb = 0.f, posb = 0.f;
    #pragma unroll
    for (int j = 0; j < NWAY; ++j) {
        const float ls = sc[j] - lse;
        const float tg = labels[b * 2 * NWAY + j];
        const float wv = labels[b * 2 * NWAY + NWAY + j];
        lossb += expf(tg) * (tg - ls);
        posb  += ls * wv;
    }
    float a = lossb, p = posb;
    #pragma unroll
    for (int d = 1; d < 64; d <<= 1) { a += __shfl_xor(a, d); p += __shfl_xor(p, d); }
    if (b == 0) out[0] = a / 512.0f - 0.1f * p;
}

extern "C" void kernel_launch(void* const* d_in, const int* in_sizes, int n_in,
                              void* d_out, int out_size, void* d_ws, size_t ws_size,
                              hipStream_t stream) {
    const float* qreps  = (const float*)d_in[0];
    const float* dreps  = (const float*)d_in[1];
    const int*   masks  = (const int*)d_in[2];
    const float* labels = (const float*)d_in[3];
    float* scoresp = (float*)d_ws;           // 512 floats
    float* out     = (float*)d_out;

    colbert_scores_kernel<<<NBLOCKS, 512, 0, stream>>>(qreps, dreps, masks, scoresp);
    colbert_loss_kernel<<<1, 64, 0, stream>>>(scoresp, labels, out);
}

// Round 13
// 18.697 us; speedup vs baseline: 1.0524x; 1.0524x over previous
//
#include <hip/hip_runtime.h>
#include <hip/hip_bf16.h>

#define NB 64
#define LQ 32
#define LD 256
#define DD 128
#define NWAY 8
#define KT 64            // doc rows per tile; 4 tiles
#define NBLOCKS (NB * NWAY)   // 512
#define LDSROW 136       // 128 + 8 bf16 pad -> 272B row stride, 16B aligned

typedef __attribute__((ext_vector_type(8))) short short8;
typedef __attribute__((ext_vector_type(4))) float f32x4;

static __device__ __forceinline__ unsigned short f2bf(float f) {
    unsigned int u = __float_as_uint(f);
    u += 0x7fffu + ((u >> 16) & 1u);   // round-to-nearest-even
    return (unsigned short)(u >> 16);
}
static __device__ __forceinline__ unsigned int pk2(float a, float b) {
    return (unsigned int)f2bf(a) | ((unsigned int)f2bf(b) << 16);
}

// One block per (b,n), 512 threads = 8 waves (wave = kq*2+qh).
// b=bid&63, n=bid>>6: the 8 blocks sharing b land on one XCD -> Q L2-hits.
// R10 pipeline with ONE change: t0/t1 doc loads issue UNGATED as the first
// instructions (breaks the mask-load -> doc-load serial chain at entry; the
// extra masked-row bytes are L3-warm and cheap). t2/t3 keep the mask gate
// (free by then). Max-gating via register cmask exactly as R10.
// Doc rows unnormalized bf16; 1/||d|| post-MFMA (max commutes with positive
// scales). launch_bounds(512,4): 128-VGPR cap, no spill (R8/R11 lesson).
__global__ __launch_bounds__(512, 4) void colbert_scores_kernel(
    const float* __restrict__ qreps,   // [B][LQ][DD]
    const float* __restrict__ dreps,   // [B][NWAY][LD][DD]
    const int*   __restrict__ masks,   // [B][NWAY][LD]
    float*       __restrict__ scores)  // [512]
{
    const int bid  = blockIdx.x;
    const int b    = bid & 63;
    const int n    = bid >> 6;
    const int bn   = b * NWAY + n;
    const int tid  = threadIdx.x;
    const int lane = tid & 63;
    const int w    = tid >> 6;

    __shared__ __align__(16) unsigned short qs[LQ * LDSROW];       // normalized q bf16
    __shared__ __align__(16) unsigned short dsb[2][KT * LDSROW];   // raw doc bf16, dbuf
    __shared__ float rnds[2][KT];
    __shared__ float qmaxs[4][LQ];

    const int row = tid >> 3;          // doc staging row (0..63)
    const int seg = tid & 7;           // 16-float segment
    const int fr  = lane & 15;
    const int fp  = lane >> 4;
    const int qh  = w & 1;
    const int kq  = w >> 1;            // 0..3

    float va[16], vb[16];

    // ---- FIRST: ungated t0/t1 doc loads (no dependency on anything) ----
    {
        const float* src0 = dreps + ((size_t)bn * LD + 0 * KT + row) * DD + seg * 16;
        const float* src1 = dreps + ((size_t)bn * LD + 1 * KT + row) * DD + seg * 16;
        #pragma unroll
        for (int i = 0; i < 4; ++i) {
            float4 f = reinterpret_cast<const float4*>(src0)[i];
            va[4*i] = f.x; va[4*i+1] = f.y; va[4*i+2] = f.z; va[4*i+3] = f.w;
        }
        #pragma unroll
        for (int i = 0; i < 4; ++i) {
            float4 f = reinterpret_cast<const float4*>(src1)[i];
            vb[4*i] = f.x; vb[4*i+1] = f.y; vb[4*i+2] = f.z; vb[4*i+3] = f.w;
        }
    }

    // ---- masks -> registers (row gates for t2/t3 + mfma column gates) ----
    int mymask[4], cmask[4];
    #pragma unroll
    for (int t = 0; t < 4; ++t) {
        mymask[t] = masks[(size_t)bn * LD + t * KT + row];
        cmask[t]  = masks[(size_t)bn * LD + t * KT + kq * 16 + fr];
    }

    // ---- Q: 16 threads/row (8 floats each) ----
    {
        const int qrow = tid >> 4;     // 0..31
        const int qseg = tid & 15;     // 8-float segment
        const float* qsrc = qreps + ((size_t)b * LQ + qrow) * DD + qseg * 8;
        float4 qa = reinterpret_cast<const float4*>(qsrc)[0];
        float4 qb = reinterpret_cast<const float4*>(qsrc)[1];
        float ss = qa.x*qa.x + qa.y*qa.y + qa.z*qa.z + qa.w*qa.w
                 + qb.x*qb.x + qb.y*qb.y + qb.z*qb.z + qb.w*qb.w;
        ss += __shfl_xor(ss, 1); ss += __shfl_xor(ss, 2);
        ss += __shfl_xor(ss, 4); ss += __shfl_xor(ss, 8);
        const float rn = rsqrtf(fmaxf(ss, 1e-24f));
        unsigned int qp[4] = { pk2(qa.x*rn, qa.y*rn), pk2(qa.z*rn, qa.w*rn),
                               pk2(qb.x*rn, qb.y*rn), pk2(qb.z*rn, qb.w*rn) };
        unsigned short* dst = &qs[qrow * LDSROW + qseg * 8];
        *reinterpret_cast<uint4*>(dst) = *reinterpret_cast<const uint4*>(qp);
    }

    // gated prefetch for t2/t3 (mask regs long since arrived -> gate is free)
    auto prefetch = [&](float (&v)[16], int t) {
        if (mymask[t]) {
            const float* src = dreps + ((size_t)bn * LD + t * KT + row) * DD + seg * 16;
            #pragma unroll
            for (int i = 0; i < 4; ++i) {
                float4 f = reinterpret_cast<const float4*>(src)[i];
                v[4*i] = f.x; v[4*i+1] = f.y; v[4*i+2] = f.z; v[4*i+3] = f.w;
            }
        }
    };
    // pack-only staging; 'gated' skips work for masked rows when safe.
    auto stagewrite = [&](float (&v)[16], int t, int bf, bool gated) {
        if (!gated || mymask[t]) {
            unsigned int dp[8];
            #pragma unroll
            for (int i = 0; i < 8; ++i) dp[i] = pk2(v[2*i], v[2*i+1]);
            unsigned short* dst = &dsb[bf][row * LDSROW + seg * 16];
            reinterpret_cast<uint4*>(dst)[0] = *reinterpret_cast<const uint4*>(&dp[0]);
            reinterpret_cast<uint4*>(dst)[1] = *reinterpret_cast<const uint4*>(&dp[4]);
            float ss = 0.f;
            #pragma unroll
            for (int i = 0; i < 16; ++i) ss += v[i] * v[i];
            ss += __shfl_xor(ss, 1); ss += __shfl_xor(ss, 2); ss += __shfl_xor(ss, 4);
            if (seg == 0) rnds[bf][row] = rsqrtf(fmaxf(ss, 1e-24f));
        }
    };

    float rmax[4] = {-1e30f, -1e30f, -1e30f, -1e30f};
    short8 afr[4];

    auto mfma_max = [&](int t, int bf) {
        const int drow = kq * 16 + fr;     // doc row within tile -> output column
        const unsigned short* bptr = &dsb[bf][drow * LDSROW + fp * 8];
        f32x4 acc = {0.f, 0.f, 0.f, 0.f};
        #pragma unroll
        for (int kc = 0; kc < 4; ++kc) {
            short8 bb = *reinterpret_cast<const short8*>(bptr + kc * 32);
            acc = __builtin_amdgcn_mfma_f32_16x16x32_bf16(afr[kc], bb, acc, 0, 0, 0);
        }
        if (cmask[t]) {
            const float rnd = rnds[bf][drow];
            #pragma unroll
            for (int r = 0; r < 4; ++r) rmax[r] = fmaxf(rmax[r], acc[r] * rnd);
        }
    };

    // ---- 4-tile pipeline, 2 LDS buffers, distance-2 register prefetch ----
    stagewrite(va, 0, 0, false);   // t0 unconditional (loaded ungated)
    __syncthreads();               // dsb[0] (t0) + qs ready

    // hoist A-fragments once (register reuse across all 4 tiles)
    {
        const unsigned short* ap = &qs[(qh * 16 + fr) * LDSROW + fp * 8];
        #pragma unroll
        for (int kc = 0; kc < 4; ++kc)
            afr[kc] = *reinterpret_cast<const short8*>(ap + kc * 32);
    }

    prefetch(va, 2);
    mfma_max(0, 0);                // read dsb[0]
    stagewrite(vb, 1, 1, false);   // t1 unconditional -> write dsb[1]
    __syncthreads();               // dsb[1] (t1) ready, dsb[0] free
    prefetch(vb, 3);
    mfma_max(1, 1);
    stagewrite(va, 2, 0, true);
    __syncthreads();
    mfma_max(2, 0);
    stagewrite(vb, 3, 1, true);
    __syncthreads();
    mfma_max(3, 1);

    // ---- reduce max over 16 doc-columns within wave ----
    #pragma unroll
    for (int r = 0; r < 4; ++r) {
        float m = rmax[r];
        m = fmaxf(m, __shfl_xor(m, 1));
        m = fmaxf(m, __shfl_xor(m, 2));
        m = fmaxf(m, __shfl_xor(m, 4));
        m = fmaxf(m, __shfl_xor(m, 8));
        rmax[r] = m;
    }
    if (fr == 0) {
        const int qr = qh * 16 + fp * 4;
        #pragma unroll
        for (int r = 0; r < 4; ++r) qmaxs[kq][qr + r] = rmax[r];
    }
    __syncthreads();

    // ---- combine k-quarters, sum over q rows, store score ----
    if (w == 0) {
        float s = 0.f;
        if (lane < 32)
            s = fmaxf(fmaxf(qmaxs[0][lane], qmaxs[1][lane]),
                      fmaxf(qmaxs[2][lane], qmaxs[3][lane]));
        s += __shfl_xor(s, 1);  s += __shfl_xor(s, 2);  s += __shfl_xor(s, 4);
        s += __shfl_xor(s, 8);  s += __shfl_xor(s, 16); s += __shfl_xor(s, 32);
        if (lane == 0) scores[bn] = s;
    }
}

// One wave: thread b handles batch row b.
__global__ __launch_bounds__(64) void colbert_loss_kernel(
    const float* __restrict__ scores,   // [512]
    const float* __restrict__ labels,   // [B][2*NWAY]
    float*       __restrict__ out)
{
    const int b = threadIdx.x;
    float sc[NWAY];
    float m = -1e30f;
    #pragma unroll
    for (int j = 0; j < NWAY; ++j) { sc[j] = scores[b * NWAY + j]; m = fmaxf(m, sc[j]); }
    float se = 0.f;
    #pragma unroll
    for (int j = 0; j < NWAY; ++j) se += expf(sc[j] - m);
    const float lse = m + logf(se);

    float lossb = 0.f, posb = 0.f;
    #pragma unroll
    for (int j = 0; j < NWAY; ++j) {
        const float ls = sc[j] - lse;
        const float tg = labels[b * 2 * NWAY + j];
        const float wv = labels[b * 2 * NWAY + NWAY + j];
        lossb += expf(tg) * (tg - ls);
        posb  += ls * wv;
    }
    float a = lossb, p = posb;
    #pragma unroll
    for (int d = 1; d < 64; d <<= 1) { a += __shfl_xor(a, d); p += __shfl_xor(p, d); }
    if (b == 0) out[0] = a / 512.0f - 0.1f * p;
}

extern "C" void kernel_launch(void* const* d_in, const int* in_sizes, int n_in,
                              void* d_out, int out_size, void* d_ws, size_t ws_size,
                              hipStream_t stream) {
    const float* qreps  = (const float*)d_in[0];
    const float* dreps  = (const float*)d_in[1];
    const int*   masks  = (const int*)d_in[2];
    const float* labels = (const float*)d_in[3];
    float* scoresp = (float*)d_ws;           // 512 floats
    float* out     = (float*)d_out;

    colbert_scores_kernel<<<NBLOCKS, 512, 0, stream>>>(qreps, dreps, masks, scoresp);
    colbert_loss_kernel<<<1, 64, 0, stream>>>(scoresp, labels, out);
}

// Round 14
// 14.946 us; speedup vs baseline: 1.3165x; 1.2510x over previous
//
#include <hip/hip_runtime.h>
#include <hip/hip_bf16.h>

#define NB 64
#define LQ 32
#define LD 256
#define DD 128
#define NWAY 8
#define KT 64            // doc rows per tile; 4 tiles
#define NBLOCKS (NB * NWAY)   // 512
#define LDSROW 136       // 128 + 8 bf16 pad -> 272B row stride, 16B aligned

typedef __attribute__((ext_vector_type(8))) short short8;
typedef __attribute__((ext_vector_type(4))) float f32x4;

static __device__ __forceinline__ unsigned short f2bf(float f) {
    unsigned int u = __float_as_uint(f);
    u += 0x7fffu + ((u >> 16) & 1u);   // round-to-nearest-even
    return (unsigned short)(u >> 16);
}
static __device__ __forceinline__ unsigned int pk2(float a, float b) {
    return (unsigned int)f2bf(a) | ((unsigned int)f2bf(b) << 16);
}

// R10 == best measured (14.78 us). One block per (b,n), 512 threads = 8 waves
// (wave = kq*2+qh). b=bid&63, n=bid>>6: the 8 blocks sharing b land on one
// XCD -> Q L2-hits. ALL masks in registers at cycle 0 (gated doc prefetch has
// no barrier dependency), all 512 threads share Q normalize (16 thr/row),
// A-fragments hoisted to registers once after barrier #1. Doc rows stored
// unnormalized bf16; 1/||d|| applied post-MFMA (max commutes with positive
// scales). Masked rows never loaded. launch_bounds(512,4): 128-VGPR cap,
// no spill (R8/R11 lesson: tighter caps spill catastrophically).
__global__ __launch_bounds__(512, 4) void colbert_scores_kernel(
    const float* __restrict__ qreps,   // [B][LQ][DD]
    const float* __restrict__ dreps,   // [B][NWAY][LD][DD]
    const int*   __restrict__ masks,   // [B][NWAY][LD]
    float*       __restrict__ scores)  // [512]
{
    const int bid  = blockIdx.x;
    const int b    = bid & 63;
    const int n    = bid >> 6;
    const int bn   = b * NWAY + n;
    const int tid  = threadIdx.x;
    const int lane = tid & 63;
    const int w    = tid >> 6;

    __shared__ __align__(16) unsigned short qs[LQ * LDSROW];       // normalized q bf16
    __shared__ __align__(16) unsigned short dsb[2][KT * LDSROW];   // raw doc bf16, dbuf
    __shared__ float rnds[2][KT];
    __shared__ float qmaxs[4][LQ];

    const int row = tid >> 3;          // doc staging row (0..63)
    const int seg = tid & 7;           // 16-float segment
    const int fr  = lane & 15;
    const int fp  = lane >> 4;
    const int qh  = w & 1;
    const int kq  = w >> 1;            // 0..3

    // ---- cycle 0: ALL masks -> registers (row gates + my mfma column gates) ----
    int mymask[4], cmask[4];
    #pragma unroll
    for (int t = 0; t < 4; ++t) {
        mymask[t] = masks[(size_t)bn * LD + t * KT + row];
        cmask[t]  = masks[(size_t)bn * LD + t * KT + kq * 16 + fr];
    }

    // ---- Q: 16 threads/row (8 floats each), issue loads early ----
    {
        const int qrow = tid >> 4;     // 0..31
        const int qseg = tid & 15;     // 8-float segment
        const float* qsrc = qreps + ((size_t)b * LQ + qrow) * DD + qseg * 8;
        float4 qa = reinterpret_cast<const float4*>(qsrc)[0];
        float4 qb = reinterpret_cast<const float4*>(qsrc)[1];
        float ss = qa.x*qa.x + qa.y*qa.y + qa.z*qa.z + qa.w*qa.w
                 + qb.x*qb.x + qb.y*qb.y + qb.z*qb.z + qb.w*qb.w;
        ss += __shfl_xor(ss, 1); ss += __shfl_xor(ss, 2);
        ss += __shfl_xor(ss, 4); ss += __shfl_xor(ss, 8);
        const float rn = rsqrtf(fmaxf(ss, 1e-24f));
        unsigned int qp[4] = { pk2(qa.x*rn, qa.y*rn), pk2(qa.z*rn, qa.w*rn),
                               pk2(qb.x*rn, qb.y*rn), pk2(qb.z*rn, qb.w*rn) };
        unsigned short* dst = &qs[qrow * LDSROW + qseg * 8];
        *reinterpret_cast<uint4*>(dst) = *reinterpret_cast<const uint4*>(qp);
    }

    float va[16], vb[16];

    // gated on REGISTER mask -> doc loads issue with no barrier dependency
    auto prefetch = [&](float (&v)[16], int t) {
        if (mymask[t]) {
            const float* src = dreps + ((size_t)bn * LD + t * KT + row) * DD + seg * 16;
            #pragma unroll
            for (int i = 0; i < 4; ++i) {
                float4 f = reinterpret_cast<const float4*>(src)[i];
                v[4*i] = f.x; v[4*i+1] = f.y; v[4*i+2] = f.z; v[4*i+3] = f.w;
            }
        }
    };
    // pack-only staging; mymask uniform across the row's 8 lanes -> shfl safe
    auto stagewrite = [&](float (&v)[16], int t, int bf) {
        if (mymask[t]) {
            unsigned int dp[8];
            #pragma unroll
            for (int i = 0; i < 8; ++i) dp[i] = pk2(v[2*i], v[2*i+1]);
            unsigned short* dst = &dsb[bf][row * LDSROW + seg * 16];
            reinterpret_cast<uint4*>(dst)[0] = *reinterpret_cast<const uint4*>(&dp[0]);
            reinterpret_cast<uint4*>(dst)[1] = *reinterpret_cast<const uint4*>(&dp[4]);
            float ss = 0.f;
            #pragma unroll
            for (int i = 0; i < 16; ++i) ss += v[i] * v[i];
            ss += __shfl_xor(ss, 1); ss += __shfl_xor(ss, 2); ss += __shfl_xor(ss, 4);
            if (seg == 0) rnds[bf][row] = rsqrtf(fmaxf(ss, 1e-24f));
        }
    };

    float rmax[4] = {-1e30f, -1e30f, -1e30f, -1e30f};
    short8 afr[4];

    auto mfma_max = [&](int t, int bf) {
        const int drow = kq * 16 + fr;     // doc row within tile -> output column
        const unsigned short* bptr = &dsb[bf][drow * LDSROW + fp * 8];
        f32x4 acc = {0.f, 0.f, 0.f, 0.f};
        #pragma unroll
        for (int kc = 0; kc < 4; ++kc) {
            short8 bb = *reinterpret_cast<const short8*>(bptr + kc * 32);
            acc = __builtin_amdgcn_mfma_f32_16x16x32_bf16(afr[kc], bb, acc, 0, 0, 0);
        }
        if (cmask[t]) {
            const float rnd = rnds[bf][drow];
            #pragma unroll
            for (int r = 0; r < 4; ++r) rmax[r] = fmaxf(rmax[r], acc[r] * rnd);
        }
    };

    // ---- 4-tile pipeline, 2 LDS buffers, distance-2 register prefetch ----
    prefetch(va, 0);  prefetch(vb, 1);
    stagewrite(va, 0, 0);
    __syncthreads();               // dsb[0] (t0) + qs ready

    // hoist A-fragments once (register reuse across all 4 tiles)
    {
        const unsigned short* ap = &qs[(qh * 16 + fr) * LDSROW + fp * 8];
        #pragma unroll
        for (int kc = 0; kc < 4; ++kc)
            afr[kc] = *reinterpret_cast<const short8*>(ap + kc * 32);
    }

    prefetch(va, 2);
    mfma_max(0, 0);                // read dsb[0]
    stagewrite(vb, 1, 1);          // write dsb[1]
    __syncthreads();               // dsb[1] (t1) ready, dsb[0] free
    prefetch(vb, 3);
    mfma_max(1, 1);
    stagewrite(va, 2, 0);
    __syncthreads();
    mfma_max(2, 0);
    stagewrite(vb, 3, 1);
    __syncthreads();
    mfma_max(3, 1);

    // ---- reduce max over 16 doc-columns within wave ----
    #pragma unroll
    for (int r = 0; r < 4; ++r) {
        float m = rmax[r];
        m = fmaxf(m, __shfl_xor(m, 1));
        m = fmaxf(m, __shfl_xor(m, 2));
        m = fmaxf(m, __shfl_xor(m, 4));
        m = fmaxf(m, __shfl_xor(m, 8));
        rmax[r] = m;
    }
    if (fr == 0) {
        const int qr = qh * 16 + fp * 4;
        #pragma unroll
        for (int r = 0; r < 4; ++r) qmaxs[kq][qr + r] = rmax[r];
    }
    __syncthreads();

    // ---- combine k-quarters, sum over q rows, store score ----
    if (w == 0) {
        float s = 0.f;
        if (lane < 32)
            s = fmaxf(fmaxf(qmaxs[0][lane], qmaxs[1][lane]),
                      fmaxf(qmaxs[2][lane], qmaxs[3][lane]));
        s += __shfl_xor(s, 1);  s += __shfl_xor(s, 2);  s += __shfl_xor(s, 4);
        s += __shfl_xor(s, 8);  s += __shfl_xor(s, 16); s += __shfl_xor(s, 32);
        if (lane == 0) scores[bn] = s;
    }
}

// One wave: thread b handles batch row b.
__global__ __launch_bounds__(64) void colbert_loss_kernel(
    const float* __restrict__ scores,   // [512]
    const float* __restrict__ labels,   // [B][2*NWAY]
    float*       __restrict__ out)
{
    const int b = threadIdx.x;
    float sc[NWAY];
    float m = -1e30f;
    #pragma unroll
    for (int j = 0; j < NWAY; ++j) { sc[j] = scores[b * NWAY + j]; m = fmaxf(m, sc[j]); }
    float se = 0.f;
    #pragma unroll
    for (int j = 0; j < NWAY; ++j) se += expf(sc[j] - m);
    const float lse = m + logf(se);

    float lossb = 0.f, posb = 0.f;
    #pragma unroll
    for (int j = 0; j < NWAY; ++j) {
        const float ls = sc[j] - lse;
        const float tg = labels[b * 2 * NWAY + j];
        const float wv = labels[b * 2 * NWAY + NWAY + j];
        lossb += expf(tg) * (tg - ls);
        posb  += ls * wv;
    }
    float a = lossb, p = posb;
    #pragma unroll
    for (int d = 1; d < 64; d <<= 1) { a += __shfl_xor(a, d); p += __shfl_xor(p, d); }
    if (b == 0) out[0] = a / 512.0f - 0.1f * p;
}

extern "C" void kernel_launch(void* const* d_in, const int* in_sizes, int n_in,
                              void* d_out, int out_size, void* d_ws, size_t ws_size,
                              hipStream_t stream) {
    const float* qreps  = (const float*)d_in[0];
    const float* dreps  = (const float*)d_in[1];
    const int*   masks  = (const int*)d_in[2];
    const float* labels = (const float*)d_in[3];
    float* scoresp = (float*)d_ws;           // 512 floats
    float* out     = (float*)d_out;

    colbert_scores_kernel<<<NBLOCKS, 512, 0, stream>>>(qreps, dreps, masks, scoresp);
    colbert_loss_kernel<<<1, 64, 0, stream>>>(scoresp, labels, out);
}